// Round 1
// baseline (477.668 us; speedup 1.0000x reference)
//
#include <hip/hip_runtime.h>

#define E_ 4032
#define TE 128

typedef unsigned int uint;
typedef unsigned short ushort;
typedef __attribute__((ext_vector_type(8))) short short8;
typedef __attribute__((ext_vector_type(4))) float f32x4;

__device__ __forceinline__ ushort f2bf(float x) {
  uint u = __float_as_uint(x);
  return (ushort)((u + 0x7fffu + ((u >> 16) & 1u)) >> 16);  // RNE f32->bf16
}
__device__ __forceinline__ uint pack2(float lo, float hi) {
  return (uint)f2bf(lo) | ((uint)f2bf(hi) << 16);
}
__device__ __forceinline__ float bflo(uint u) { return __uint_as_float(u << 16); }
__device__ __forceinline__ float bfhi(uint u) { return __uint_as_float(u & 0xffff0000u); }
__device__ __forceinline__ float bf2f(ushort s) { return __uint_as_float((uint)s << 16); }
__device__ __forceinline__ float rcp_(float x) { return __builtin_amdgcn_rcpf(x); }
__device__ __forceinline__ float silu_(float v) { return v * rcp_(1.0f + __expf(-v)); }
__device__ __forceinline__ float sigmoid_(float v) { return rcp_(1.0f + __expf(-v)); }
__device__ __forceinline__ float tanh_(float v) { return 1.0f - 2.0f * rcp_(1.0f + __expf(2.0f * v)); }

// 128x256 (A, LDS, swizzled bf16) @ 256x256 (B = WT[n][k] bf16, L2-streamed) -> acc
// wave w owns rows 0..127 x cols [w*64, w*64+64)
__device__ __forceinline__ void gemm128(const ushort* Ab, const ushort* Bmat,
                                        int w, int l15, int lhi, f32x4 acc[8][4]) {
#pragma unroll
  for (int ks = 0; ks < 8; ++ks) {
    short8 av[8];
#pragma unroll
    for (int rm = 0; rm < 8; ++rm) {
      int row = rm * 16 + l15;
      int byt = (ks * 64 + lhi * 16) ^ ((row & 7) << 4);
      av[rm] = *(const short8*)((const char*)Ab + row * 512 + byt);
    }
#pragma unroll
    for (int cn = 0; cn < 4; ++cn) {
      int col = w * 64 + cn * 16 + l15;
      short8 bv = *(const short8*)(Bmat + col * 256 + ks * 32 + lhi * 8);
#pragma unroll
      for (int rm = 0; rm < 8; ++rm)
        acc[rm][cn] = __builtin_amdgcn_mfma_f32_16x16x32_bf16(av[rm], bv, acc[rm][cn], 0, 0, 0);
    }
  }
}

// WT[9][256][256] bf16, WT[m][n][k] = srcm[k*256 + n]
__global__ __launch_bounds__(256) void k_prep(
    const float* __restrict__ We1, const float* __restrict__ Wx1,
    const float* __restrict__ Wh1, const float* __restrict__ We2,
    const float* __restrict__ Wx2, const float* __restrict__ Wh2,
    ushort* __restrict__ WT) {
  __shared__ float tl[64][65];
  int blk = blockIdx.x;
  int m = blk >> 4, tile = blk & 15;
  int kt = (tile & 3) * 64, nt = (tile >> 2) * 64;
  const float* src;
  switch (m) {
    case 0: src = We1; break;
    case 1: src = We1 + 65536; break;
    case 2: src = Wx1; break;
    case 3: src = Wx1 + 65536; break;
    case 4: src = Wh1; break;
    case 5: src = We2; break;
    case 6: src = Wx2; break;
    case 7: src = Wh1 + 65536; break;
    default: src = Wh2; break;
  }
  int t = threadIdx.x;
  int c = t & 63, r4 = t >> 6;
#pragma unroll
  for (int rr = 0; rr < 64; rr += 4)
    tl[rr + r4][c] = src[(size_t)(kt + rr + r4) * 256 + nt + c];
  __syncthreads();
#pragma unroll
  for (int rr = 0; rr < 64; rr += 4)
    WT[(size_t)m * 65536 + (size_t)(nt + rr + r4) * 256 + kt + c] = f2bf(tl[c][rr + r4]);
}

// P[4096][1280] bf16 = h @ [We1L|We1R|Wx1L|Wx1R|Wh1top]
__global__ __launch_bounds__(256, 2) void k_proj(const float* __restrict__ h,
                                                 const ushort* __restrict__ WT,
                                                 ushort* __restrict__ P) {
  __shared__ ushort Ab[128 * 256];
  int t = threadIdx.x;
  int rowbase = (blockIdx.x & 31) * 128;
  int g = blockIdx.x >> 5;  // 0..4
  {
    int c2 = t & 127, es = t >> 7;
#pragma unroll 4
    for (int it = 0; it < 64; ++it) {
      int row = it * 2 + es;
      float2 v = *(const float2*)(h + (size_t)(rowbase + row) * 256 + c2 * 2);
      *(uint*)((char*)Ab + row * 512 + ((c2 * 4) ^ ((row & 7) << 4))) = pack2(v.x, v.y);
    }
  }
  __syncthreads();
  int w = t >> 6, lane = t & 63, l15 = lane & 15, lhi = lane >> 4;
  f32x4 acc[8][4] = {};
  gemm128(Ab, WT + g * 65536, w, l15, lhi, acc);
#pragma unroll
  for (int rm = 0; rm < 8; ++rm)
#pragma unroll
    for (int cn = 0; cn < 4; ++cn)
#pragma unroll
      for (int r = 0; r < 4; ++r) {
        int row = rowbase + rm * 16 + lhi * 4 + r;
        int col = w * 64 + cn * 16 + l15;
        P[(size_t)row * 1280 + g * 256 + col] = f2bf(acc[rm][cn][r]);
      }
}

__global__ __launch_bounds__(256, 2) void k_edge(
    const float* __restrict__ x, const int* __restrict__ eidx,
    const float* __restrict__ a, const float* __restrict__ emask,
    const ushort* __restrict__ P, const ushort* __restrict__ WT,
    const float* __restrict__ We1, const float* __restrict__ be1,
    const float* __restrict__ be2, const float* __restrict__ Wa,
    const float* __restrict__ ba,
    const float* __restrict__ Wx1, const float* __restrict__ bx1,
    const float* __restrict__ bx2, const float* __restrict__ Wx3,
    float* __restrict__ em_agg, float* __restrict__ x_agg) {
  __shared__ ushort Ab[TE * 256];      // 64 KiB, swizzled T1 tile
  __shared__ uint s_i4[TE], s_j4[TE];
  __shared__ float s_d2[TE], s_rd1[TE];
  __shared__ float4 s_a4[TE];
  __shared__ float s_dx[TE], s_dy[TE], s_dz[TE];
  __shared__ float s_part[4][TE];
  __shared__ float s_gate[TE];
  int t = threadIdx.x;
  int ebase = blockIdx.x * TE;

  if (t < TE) {  // phase 0: edge meta
    int eg = ebase + t;
    int b = eg / E_;
    int2 ij = *(const int2*)(eidx + (size_t)eg * 2);
    int i4 = b * 64 + ij.x;
    int j4 = b * 64 + ij.y;
    s_i4[t] = (uint)i4;
    s_j4[t] = (uint)j4;
    float m = emask[eg];
    float dx = (x[i4 * 3 + 0] - x[j4 * 3 + 0]) * m;
    float dy = (x[i4 * 3 + 1] - x[j4 * 3 + 1]) * m;
    float dz = (x[i4 * 3 + 2] - x[j4 * 3 + 2]) * m;
    float d2 = dx * dx + dy * dy + dz * dz;
    s_d2[t] = d2;
    s_dx[t] = dx; s_dy[t] = dy; s_dz[t] = dz;
    s_rd1[t] = rcp_(sqrtf(d2) + 1.0f);
    s_a4[t] = *(const float4*)(a + (size_t)eg * 4);
  }
  __syncthreads();

  const uint* Pu = (const uint*)P;
  int w = t >> 6, lane = t & 63, l15 = lane & 15, lhi = lane >> 4;

  for (int br = 0; br < 2; ++br) {  // br=0: h/We2 branch, br=1: x/Wx2 branch
    {  // build T1 = silu(P_i + P_j + d2*w512 + a@Wrows + b1) into LDS (bf16, swizzled)
      int c2 = t & 127, es = t >> 7;
      int c0 = c2 * 2;
      const float* Wbig = br ? Wx1 : We1;
      const float* b1 = br ? bx1 : be1;
      float w5_0 = Wbig[512 * 256 + c0],  w5_1 = Wbig[512 * 256 + c0 + 1];
      float wa0_0 = Wbig[513 * 256 + c0], wa0_1 = Wbig[513 * 256 + c0 + 1];
      float wa1_0 = Wbig[514 * 256 + c0], wa1_1 = Wbig[514 * 256 + c0 + 1];
      float wa2_0 = Wbig[515 * 256 + c0], wa2_1 = Wbig[515 * 256 + c0 + 1];
      float wa3_0 = Wbig[516 * 256 + c0], wa3_1 = Wbig[516 * 256 + c0 + 1];
      float b1_0 = b1[c0], b1_1 = b1[c0 + 1];
      int offI = br ? 256 : 0;
      int offJ = offI + 128;
#pragma unroll 4
      for (int it = 0; it < 64; ++it) {
        int e = it * 2 + es;
        uint i4 = s_i4[e], j4 = s_j4[e];
        float d2 = s_d2[e];
        float4 av = s_a4[e];
        uint pi = Pu[i4 * 640u + (uint)(offI + c2)];
        uint pj = Pu[j4 * 640u + (uint)(offJ + c2)];
        float v0 = bflo(pi) + bflo(pj) + d2 * w5_0 + av.x * wa0_0 + av.y * wa1_0 +
                   av.z * wa2_0 + av.w * wa3_0 + b1_0;
        float v1 = bfhi(pi) + bfhi(pj) + d2 * w5_1 + av.x * wa0_1 + av.y * wa1_1 +
                   av.z * wa2_1 + av.w * wa3_1 + b1_1;
        *(uint*)((char*)Ab + e * 512 + ((c0 * 2) ^ ((e & 7) << 4))) =
            pack2(silu_(v0), silu_(v1));
      }
    }
    __syncthreads();
    f32x4 acc[8][4] = {};
    gemm128(Ab, WT + (br ? 6 : 5) * 65536, w, l15, lhi, acc);
    {  // epilogue: m = silu(acc + b2); row-dot with gate vector
      const float* b2 = br ? bx2 : be2;
      const float* wv = br ? Wx3 : Wa;
      float wvc[4], b2c[4];
#pragma unroll
      for (int cn = 0; cn < 4; ++cn) {
        int col = w * 64 + cn * 16 + l15;
        wvc[cn] = wv[col];
        b2c[cn] = b2[col];
      }
#pragma unroll
      for (int rm = 0; rm < 8; ++rm)
#pragma unroll
        for (int r = 0; r < 4; ++r) {
          float p = 0.f;
#pragma unroll
          for (int cn = 0; cn < 4; ++cn) {
            float mv = silu_(acc[rm][cn][r] + b2c[cn]);
            acc[rm][cn][r] = mv;
            p += mv * wvc[cn];
          }
          p += __shfl_xor(p, 1);
          p += __shfl_xor(p, 2);
          p += __shfl_xor(p, 4);
          p += __shfl_xor(p, 8);
          if (l15 == 0) s_part[w][rm * 16 + lhi * 4 + r] = p;
        }
    }
    __syncthreads();
    if (t < TE) {
      float s = s_part[0][t] + s_part[1][t] + s_part[2][t] + s_part[3][t];
      if (br == 0) {
        s_gate[t] = sigmoid_(s + ba[0]);
      } else {
        float fac = tanh_(s) * 15.0f * s_rd1[t];
        uint base = s_i4[t] * 3u;
        atomicAdd(x_agg + base + 0, fac * s_dx[t]);
        atomicAdd(x_agg + base + 1, fac * s_dy[t]);
        atomicAdd(x_agg + base + 2, fac * s_dz[t]);
      }
    }
    __syncthreads();
    if (br == 0) {  // em = e*m scatter
#pragma unroll
      for (int rm = 0; rm < 8; ++rm)
#pragma unroll
        for (int r = 0; r < 4; ++r) {
          int row = rm * 16 + lhi * 4 + r;
          float g = s_gate[row];
          uint base = s_i4[row] * 256u;
#pragma unroll
          for (int cn = 0; cn < 4; ++cn) {
            int col = w * 64 + cn * 16 + l15;
            atomicAdd(em_agg + base + col, g * acc[rm][cn][r]);
          }
        }
    }
  }
}

__global__ __launch_bounds__(256, 2) void k_node(
    const float* __restrict__ h, const float* __restrict__ x,
    const float* __restrict__ nmask,
    const float* __restrict__ em_agg, const float* __restrict__ x_agg,
    const ushort* __restrict__ P, const ushort* __restrict__ WT,
    const float* __restrict__ bh1, const float* __restrict__ bh2,
    float* __restrict__ out) {
  __shared__ ushort Ab[128 * 256];
  int t = threadIdx.x;
  int rowbase = blockIdx.x * 128;
  {
    int c2 = t & 127, es = t >> 7;
#pragma unroll 4
    for (int it = 0; it < 64; ++it) {
      int row = it * 2 + es;
      float2 v = *(const float2*)(em_agg + (size_t)(rowbase + row) * 256 + c2 * 2);
      *(uint*)((char*)Ab + row * 512 + ((c2 * 4) ^ ((row & 7) << 4))) = pack2(v.x, v.y);
    }
  }
  __syncthreads();
  int w = t >> 6, lane = t & 63, l15 = lane & 15, lhi = lane >> 4;
  {
    f32x4 acc[8][4] = {};
    gemm128(Ab, WT + 7 * 65536, w, l15, lhi, acc);  // em_agg @ Wh1bot
    __syncthreads();
    float bc[4];
#pragma unroll
    for (int cn = 0; cn < 4; ++cn) bc[cn] = bh1[w * 64 + cn * 16 + l15];
#pragma unroll
    for (int rm = 0; rm < 8; ++rm)
#pragma unroll
      for (int cn = 0; cn < 4; ++cn)
#pragma unroll
        for (int r = 0; r < 4; ++r) {
          int row = rm * 16 + lhi * 4 + r;
          int col = w * 64 + cn * 16 + l15;
          float q1 = bf2f(P[(size_t)(rowbase + row) * 1280 + 1024 + col]);  // h@Wh1top
          float sv = silu_(acc[rm][cn][r] + q1 + bc[cn]);
          *(ushort*)((char*)Ab + row * 512 + ((col * 2) ^ ((row & 7) << 4))) = f2bf(sv);
        }
  }
  __syncthreads();
  {
    f32x4 acc[8][4] = {};
    gemm128(Ab, WT + 8 * 65536, w, l15, lhi, acc);  // silu(...) @ Wh2
    float bc[4];
#pragma unroll
    for (int cn = 0; cn < 4; ++cn) bc[cn] = bh2[w * 64 + cn * 16 + l15];
#pragma unroll
    for (int rm = 0; rm < 8; ++rm)
#pragma unroll
      for (int cn = 0; cn < 4; ++cn)
#pragma unroll
        for (int r = 0; r < 4; ++r) {
          int row = rowbase + rm * 16 + lhi * 4 + r;
          int col = w * 64 + cn * 16 + l15;
          float o = (h[(size_t)row * 256 + col] + acc[rm][cn][r] + bc[cn]) * nmask[row];
          out[12288 + (size_t)row * 256 + col] = o;
        }
  }
  if (t < 128) {  // x_out
    int row = rowbase + t;
    float nm = nmask[row];
#pragma unroll
    for (int c = 0; c < 3; ++c)
      out[row * 3 + c] = (x[row * 3 + c] + x_agg[row * 3 + c]) * nm;
  }
}

extern "C" void kernel_launch(void* const* d_in, const int* in_sizes, int n_in,
                              void* d_out, int out_size, void* d_ws, size_t ws_size,
                              hipStream_t stream) {
  (void)in_sizes; (void)n_in; (void)out_size; (void)ws_size;
  const float* x = (const float*)d_in[0];
  const float* h = (const float*)d_in[1];
  const float* a = (const float*)d_in[2];
  const int* eidx = (const int*)d_in[3];
  const float* nmask = (const float*)d_in[4];
  const float* emask = (const float*)d_in[5];
  const float* We1 = (const float*)d_in[6];
  const float* be1 = (const float*)d_in[7];
  const float* be2 = (const float*)d_in[9];
  const float* Wa = (const float*)d_in[10];
  const float* ba = (const float*)d_in[11];
  const float* bh1 = (const float*)d_in[13];
  const float* bh2 = (const float*)d_in[15];
  const float* Wx1 = (const float*)d_in[16];
  const float* bx1 = (const float*)d_in[17];
  const float* bx2 = (const float*)d_in[19];
  const float* Wx3 = (const float*)d_in[20];
  const float* We2 = (const float*)d_in[8];
  const float* Wx2 = (const float*)d_in[18];
  const float* Wh1 = (const float*)d_in[12];
  const float* Wh2 = (const float*)d_in[14];

  char* ws = (char*)d_ws;
  ushort* WT = (ushort*)ws;                      //  9*65536*2  = 1,179,648 B
  ushort* P = (ushort*)(ws + 1179648);           //  4096*1280*2 = 10,485,760 B
  float* em_agg = (float*)(ws + 11665408);       //  4096*256*4 = 4,194,304 B
  float* x_agg = (float*)(ws + 15859712);        //  4096*3*4   = 49,152 B

  hipMemsetAsync(em_agg, 0, 4194304 + 49152, stream);
  k_prep<<<144, 256, 0, stream>>>(We1, Wx1, Wh1, We2, Wx2, Wh2, WT);
  k_proj<<<160, 256, 0, stream>>>(h, WT, P);
  k_edge<<<2016, 256, 0, stream>>>(x, eidx, a, emask, P, WT, We1, be1, be2, Wa, ba,
                                   Wx1, bx1, bx2, Wx3, em_agg, x_agg);
  k_node<<<32, 256, 0, stream>>>(h, x, nmask, em_agg, x_agg, P, WT, bh1, bh2,
                                 (float*)d_out);
}